// Round 1
// baseline (343.370 us; speedup 1.0000x reference)
//
#include <hip/hip_runtime.h>

// Problem constants (from reference setup_inputs)
#define B_  48
#define S_  1024
#define D_  128
#define DK_ 64
#define BS_ (B_ * S_)

typedef _Float16 f16x8 __attribute__((ext_vector_type(8)));
typedef _Float16 f16x4 __attribute__((ext_vector_type(4)));
typedef float    f32x4 __attribute__((ext_vector_type(4)));

__device__ __forceinline__ float fast_exp2(float x) {
#if __has_builtin(__builtin_amdgcn_exp2f)
    return __builtin_amdgcn_exp2f(x);
#else
    return exp2f(x);
#endif
}
__device__ __forceinline__ float fast_rcp(float x) {
#if __has_builtin(__builtin_amdgcn_rcpf)
    return __builtin_amdgcn_rcpf(x);
#else
    return 1.0f / x;
#endif
}

// ---------------------------------------------------------------------------
// K1: Q = query @ Wq, K = query @ Wk in exact fp32 (VALU), stored as fp16
// hi/lo split pairs for split-precision MFMA in K2/K3.
// grid.x = (BS/64)*2  (even blocks: Q, odd blocks: K), 256 threads.
// Each block: 64 rows x 64 cols. Thread tile 4x4. W staged in LDS (fp32).
// Also zeroes sums[] (block 0) — ws is re-poisoned before every launch.
// ---------------------------------------------------------------------------
__global__ __launch_bounds__(256) void qk_proj(
    const float* __restrict__ query,
    const float* __restrict__ Wq, const float* __restrict__ Wk,
    _Float16* __restrict__ Qhi, _Float16* __restrict__ Qlo,
    _Float16* __restrict__ Khi, _Float16* __restrict__ Klo,
    float* __restrict__ sums)
{
    __shared__ float Wl[D_][DK_ + 4];   // 128 x 68 fp32 = 34.8 KB (pad kills conflicts)

    const int t  = threadIdx.x;
    const int bx = blockIdx.x;
    const int m  = bx & 1;              // 0 = Q, 1 = K
    const int r0 = (bx >> 1) * 64;
    const float* __restrict__ Wsrc = m ? Wk : Wq;
    _Float16* __restrict__ ohi = m ? Khi : Qhi;
    _Float16* __restrict__ olo = m ? Klo : Qlo;

    if (bx == 0 && t < B_) sums[t] = 0.0f;

    // Stage W: 128x64 fp32 = 2048 float4
    #pragma unroll
    for (int i = 0; i < 8; ++i) {
        int idx = t + i * 256;
        int row = idx >> 4;
        int c4  = (idx & 15) << 2;
        *(float4*)&Wl[row][c4] = *(const float4*)(Wsrc + row * DK_ + c4);
    }
    __syncthreads();

    const int rg = t >> 4;   // 0..15 -> rows rg*4 .. rg*4+3
    const int cg = t & 15;   // 0..15 -> cols cg*4 .. cg*4+3
    const float* __restrict__ qrow = query + (size_t)(r0 + rg * 4) * D_;

    float acc[4][4];
    #pragma unroll
    for (int r = 0; r < 4; ++r)
        #pragma unroll
        for (int c = 0; c < 4; ++c) acc[r][c] = 0.0f;

    for (int k = 0; k < D_; k += 4) {
        float qv[4][4], wv[4][4];
        #pragma unroll
        for (int dr = 0; dr < 4; ++dr) {
            float4 v = *(const float4*)(qrow + (size_t)dr * D_ + k);
            qv[dr][0] = v.x; qv[dr][1] = v.y; qv[dr][2] = v.z; qv[dr][3] = v.w;
        }
        #pragma unroll
        for (int dk = 0; dk < 4; ++dk) {
            float4 v = *(const float4*)&Wl[k + dk][cg * 4];
            wv[dk][0] = v.x; wv[dk][1] = v.y; wv[dk][2] = v.z; wv[dk][3] = v.w;
        }
        #pragma unroll
        for (int dr = 0; dr < 4; ++dr)
            #pragma unroll
            for (int dk = 0; dk < 4; ++dk)
                #pragma unroll
                for (int dc = 0; dc < 4; ++dc)
                    acc[dr][dc] = fmaf(qv[dr][dk], wv[dk][dc], acc[dr][dc]);
    }

    // Store hi/lo fp16 split: hi = fp16(x), lo = fp16(x - hi)
    #pragma unroll
    for (int dr = 0; dr < 4; ++dr) {
        f16x4 h, l;
        #pragma unroll
        for (int dc = 0; dc < 4; ++dc) {
            float x = acc[dr][dc];
            _Float16 hi = (_Float16)x;
            h[dc] = hi;
            l[dc] = (_Float16)(x - (float)hi);
        }
        size_t off = (size_t)(r0 + rg * 4 + dr) * DK_ + cg * 4;
        *(f16x4*)(ohi + off) = h;
        *(f16x4*)(olo + off) = l;
    }
}

// ---------------------------------------------------------------------------
// K2/K3: scores = Q·K^T via split-precision fp16 MFMA (3 terms), fused
// tanh->exp epilogue. WRITE=false: accumulate per-batch sum of exp values.
// WRITE=true: recompute, scale by 1/sum, write output.
// grid = (64, 48): 128x128 tile per block per batch. 256 thr = 4 waves (2x2),
// each wave a 64x64 tile = 4x4 grid of 16x16 MFMA tiles, K=64 (2 chunks).
// e = exp(10*tanh(x) - 10) = 2^( -20*log2(e) / (2^(x*2*log2(e)) + 1) )
// ---------------------------------------------------------------------------
template <bool WRITE>
__global__ __launch_bounds__(256) void score_k(
    const _Float16* __restrict__ Qhi, const _Float16* __restrict__ Qlo,
    const _Float16* __restrict__ Khi, const _Float16* __restrict__ Klo,
    float* __restrict__ sums, float* __restrict__ out)
{
    const int b    = blockIdx.y;
    const int tile = blockIdx.x;
    const int qt   = (tile >> 3) * 128;
    const int st   = (tile & 7) * 128;
    const int t    = threadIdx.x;
    const int lane = t & 63;
    const int wave = t >> 6;
    const int qbase = qt + (wave >> 1) * 64;
    const int sbase = st + (wave & 1) * 64;
    const int row15 = lane & 15;
    const int quad  = lane >> 4;

    const size_t boff = (size_t)b * (S_ * DK_);
    // 3-term split product: Qhi*Khi + Qhi*Klo + Qlo*Khi (lo*lo dropped, ~2e-6)
    const _Float16* __restrict__ Asrc[3] = { Qhi + boff, Qhi + boff, Qlo + boff };
    const _Float16* __restrict__ Bsrc[3] = { Khi + boff, Klo + boff, Khi + boff };

    f32x4 acc[4][4];
    #pragma unroll
    for (int i = 0; i < 4; ++i)
        #pragma unroll
        for (int j = 0; j < 4; ++j)
            acc[i][j] = (f32x4){0.f, 0.f, 0.f, 0.f};

    const int aoff = quad * 8;  // k offset within 32-chunk: lane quad * 8

    #pragma unroll
    for (int term = 0; term < 3; ++term) {
        const _Float16* __restrict__ Ab = Asrc[term];
        const _Float16* __restrict__ Bb = Bsrc[term];
        #pragma unroll
        for (int kc = 0; kc < 2; ++kc) {
            f16x8 Af[4], Bf[4];
            #pragma unroll
            for (int i = 0; i < 4; ++i) {
                Af[i] = *(const f16x8*)(Ab + (size_t)(qbase + i * 16 + row15) * DK_ + kc * 32 + aoff);
                Bf[i] = *(const f16x8*)(Bb + (size_t)(sbase + i * 16 + row15) * DK_ + kc * 32 + aoff);
            }
            #pragma unroll
            for (int rt = 0; rt < 4; ++rt)
                #pragma unroll
                for (int ct = 0; ct < 4; ++ct)
                    acc[rt][ct] = __builtin_amdgcn_mfma_f32_16x16x32_f16(
                        Af[rt], Bf[ct], acc[rt][ct], 0, 0, 0);
        }
    }

    const float C2X  = 2.8853900817779268f;    //  2*log2(e)
    const float CEXP = -28.853900817779268f;   // -20*log2(e)

    float lsum = 0.0f;
    float inv = 0.0f;
    float* __restrict__ outb = nullptr;
    if (WRITE) {
        inv  = 1.0f / sums[b];
        outb = out + ((size_t)b << 20);
    }

    #pragma unroll
    for (int rt = 0; rt < 4; ++rt) {
        #pragma unroll
        for (int ct = 0; ct < 4; ++ct) {
            #pragma unroll
            for (int v = 0; v < 4; ++v) {
                int q = qbase + rt * 16 + quad * 4 + v;
                int s = sbase + ct * 16 + row15;
                float x = acc[rt][ct][v];
                float u = fast_exp2(x * C2X);                 // e^(2x)
                float e = fast_exp2(CEXP * fast_rcp(u + 1.0f)); // e^(10tanh(x)-10)
                e = (q == s) ? 0.0f : e;                       // diagonal mask -> exact 0
                if (WRITE) {
                    outb[((size_t)q << 10) | (unsigned)s] = e * inv;
                } else {
                    lsum += e;
                }
            }
        }
    }

    if (!WRITE) {
        #pragma unroll
        for (int o = 32; o > 0; o >>= 1) lsum += __shfl_down(lsum, o);
        __shared__ float wsum[4];
        if (lane == 0) wsum[wave] = lsum;
        __syncthreads();
        if (t == 0) atomicAdd(&sums[b], (wsum[0] + wsum[1]) + (wsum[2] + wsum[3]));
    }
}

// ---------------------------------------------------------------------------
extern "C" void kernel_launch(void* const* d_in, const int* in_sizes, int n_in,
                              void* d_out, int out_size, void* d_ws, size_t ws_size,
                              hipStream_t stream)
{
    (void)in_sizes; (void)n_in; (void)out_size; (void)ws_size;
    const float* query = (const float*)d_in[0];
    // d_in[1] (exchange) and d_in[2] (solution_indexes) are unused by the reference.
    const float* Wq = (const float*)d_in[3];
    const float* Wk = (const float*)d_in[4];
    float* out = (float*)d_out;

    const size_t N = (size_t)BS_ * DK_;   // 3,145,728 halves per array
    _Float16* Qhi = (_Float16*)d_ws;
    _Float16* Qlo = Qhi + N;
    _Float16* Khi = Qlo + N;
    _Float16* Klo = Khi + N;
    float* sums = (float*)(Klo + N);      // 48 floats; total ws ~25.2 MB

    qk_proj<<<dim3((BS_ / 64) * 2), 256, 0, stream>>>(query, Wq, Wk,
                                                      Qhi, Qlo, Khi, Klo, sums);
    dim3 g(64, B_);
    score_k<false><<<g, 256, 0, stream>>>(Qhi, Qlo, Khi, Klo, sums, nullptr);
    score_k<true><<<g, 256, 0, stream>>>(Qhi, Qlo, Khi, Klo, sums, out);
}